// Round 1
// baseline (457.151 us; speedup 1.0000x reference)
//
#include <hip/hip_runtime.h>

// CustomQuantizer: idx = argmax(x, axis=-1); out[n, :] = W[:, idx[n]]
//   x: [N_TOKENS, QUANT_DIM] fp32   (8192 x 8192)
//   W: [OUT_DIM, QUANT_DIM]  fp32   (1024 x 8192)
//   out: [N_TOKENS, OUT_DIM] fp32   (8192 x 1024)
//
// Strategy: one block per token. 256 threads stream the 32 KiB row with
// float4 loads (coalesced), reduce (val,idx) with first-index tie-break
// (matches jnp.argmax), broadcast idx, then gather W[j][idx] for
// j=0..1023 (out write coalesced; W column read uncoalesced but W is
// 32 MiB -> fully L3-resident, reuse across the ~8192 blocks).

#define QUANT_DIM 8192
#define OUT_DIM   1024
#define BLOCK     256

__global__ __launch_bounds__(BLOCK) void quantizer_fused(
    const float* __restrict__ x,
    const float* __restrict__ W,
    float* __restrict__ out,
    int n_tokens)
{
    const int row = blockIdx.x;
    if (row >= n_tokens) return;
    const int tid = threadIdx.x;
    const float* xr = x + (size_t)row * QUANT_DIM;

    // ---- local argmax over this thread's strided-by-iteration chunks ----
    // Thread t covers indices {i*1024 + t*4 + k}; increasing i => increasing
    // index, so strict '>' keeps the FIRST max within a thread.
    float best = -INFINITY;
    int bidx = 0;
    #pragma unroll
    for (int i = 0; i < QUANT_DIM / (BLOCK * 4); ++i) {
        const int base = i * (BLOCK * 4) + tid * 4;
        const float4 v = *reinterpret_cast<const float4*>(xr + base);
        if (v.x > best) { best = v.x; bidx = base;     }
        if (v.y > best) { best = v.y; bidx = base + 1; }
        if (v.z > best) { best = v.z; bidx = base + 2; }
        if (v.w > best) { best = v.w; bidx = base + 3; }
    }

    // ---- wave (64-lane) reduction, tie-break to smaller index ----
    #pragma unroll
    for (int off = 32; off > 0; off >>= 1) {
        const float ov = __shfl_down(best, off, 64);
        const int   oi = __shfl_down(bidx, off, 64);
        if (ov > best || (ov == best && oi < bidx)) { best = ov; bidx = oi; }
    }

    // ---- cross-wave reduction via LDS (4 waves) ----
    __shared__ float sval[BLOCK / 64];
    __shared__ int   sidx[BLOCK / 64];
    __shared__ int   result;
    const int wave = tid >> 6;
    if ((tid & 63) == 0) { sval[wave] = best; sidx[wave] = bidx; }
    __syncthreads();
    if (tid == 0) {
        float b = sval[0];
        int   bi = sidx[0];
        #pragma unroll
        for (int w = 1; w < BLOCK / 64; ++w) {
            if (sval[w] > b || (sval[w] == b && sidx[w] < bi)) {
                b = sval[w]; bi = sidx[w];
            }
        }
        result = bi;
    }
    __syncthreads();
    const int idx = result;

    // ---- gather: out[row][j] = W[j][idx] ----
    float* orow = out + (size_t)row * OUT_DIM;
    #pragma unroll
    for (int j = tid; j < OUT_DIM; j += BLOCK) {
        orow[j] = W[(size_t)j * QUANT_DIM + idx];
    }
}

extern "C" void kernel_launch(void* const* d_in, const int* in_sizes, int n_in,
                              void* d_out, int out_size, void* d_ws, size_t ws_size,
                              hipStream_t stream) {
    const float* x = (const float*)d_in[0];
    const float* W = (const float*)d_in[1];
    float* out = (float*)d_out;
    const int n_tokens = in_sizes[0] / QUANT_DIM;

    quantizer_fused<<<n_tokens, BLOCK, 0, stream>>>(x, W, out, n_tokens);
}

// Round 2
// 391.172 us; speedup vs baseline: 1.1687x; 1.1687x over previous
//
#include <hip/hip_runtime.h>

// CustomQuantizer: idx = argmax(x, axis=-1); out[n, :] = W[:, idx[n]] = W.T[idx[n], :]
//   x: [N_TOKENS, QUANT_DIM] fp32   (8192 x 8192)
//   W: [OUT_DIM, QUANT_DIM]  fp32   (1024 x 8192)
//   out: [N_TOKENS, OUT_DIM] fp32   (8192 x 1024)
//
// R1 lesson (rocprof): direct column gather from W = 353 MB of HBM line
// refill (stride-32KB scatter, 128B lines, no XCD-L2 reuse) + latency
// stalls -> 3.5 TB/s, 188 us. Fix: transpose W into d_ws once per launch
// (LDS-tiled, coalesced both sides), then the gather is a contiguous
// 4 KB row copy.

#define QUANT_DIM 8192
#define OUT_DIM   1024
#define BLOCK     256
#define TDIM      32

// ---------------- W [OUT_DIM][QUANT_DIM] -> WT [QUANT_DIM][OUT_DIM] ----------------
__global__ __launch_bounds__(256) void transpose_W(
    const float* __restrict__ W, float* __restrict__ WT)
{
    __shared__ float tile[TDIM][TDIM + 1];   // +1 pad: kill bank conflicts
    const int bx = blockIdx.x;               // quant-dim tile (QUANT_DIM/32)
    const int by = blockIdx.y;               // out-dim tile   (OUT_DIM/32)
    const int tx = threadIdx.x;              // 0..31
    const int ty = threadIdx.y;              // 0..7

    // read: coalesced along W's row (quant dim)
    const int xq = bx * TDIM + tx;
    #pragma unroll
    for (int j = 0; j < TDIM; j += 8) {
        const int yo = by * TDIM + ty + j;
        tile[ty + j][tx] = W[(size_t)yo * QUANT_DIM + xq];
    }
    __syncthreads();

    // write: coalesced along WT's row (out dim)
    const int xo = by * TDIM + tx;
    #pragma unroll
    for (int j = 0; j < TDIM; j += 8) {
        const int yq = bx * TDIM + ty + j;
        WT[(size_t)yq * OUT_DIM + xo] = tile[tx][ty + j];
    }
}

// ---------------- fused argmax + coalesced gather from WT ----------------
__global__ __launch_bounds__(BLOCK) void quantizer_fused_wt(
    const float* __restrict__ x,
    const float* __restrict__ WT,
    float* __restrict__ out,
    int n_tokens)
{
    const int row = blockIdx.x;
    if (row >= n_tokens) return;
    const int tid = threadIdx.x;
    const float* xr = x + (size_t)row * QUANT_DIM;

    // local argmax; per-thread indices increase with i -> strict '>' keeps first
    float best = -INFINITY;
    int bidx = 0;
    #pragma unroll
    for (int i = 0; i < QUANT_DIM / (BLOCK * 4); ++i) {
        const int base = i * (BLOCK * 4) + tid * 4;
        const float4 v = *reinterpret_cast<const float4*>(xr + base);
        if (v.x > best) { best = v.x; bidx = base;     }
        if (v.y > best) { best = v.y; bidx = base + 1; }
        if (v.z > best) { best = v.z; bidx = base + 2; }
        if (v.w > best) { best = v.w; bidx = base + 3; }
    }

    // wave (64-lane) reduction, tie-break to smaller index
    #pragma unroll
    for (int off = 32; off > 0; off >>= 1) {
        const float ov = __shfl_down(best, off, 64);
        const int   oi = __shfl_down(bidx, off, 64);
        if (ov > best || (ov == best && oi < bidx)) { best = ov; bidx = oi; }
    }

    // cross-wave reduction via LDS (4 waves)
    __shared__ float sval[BLOCK / 64];
    __shared__ int   sidx[BLOCK / 64];
    __shared__ int   result;
    const int wave = tid >> 6;
    if ((tid & 63) == 0) { sval[wave] = best; sidx[wave] = bidx; }
    __syncthreads();
    if (tid == 0) {
        float b = sval[0];
        int   bi = sidx[0];
        #pragma unroll
        for (int w = 1; w < BLOCK / 64; ++w) {
            if (sval[w] > b || (sval[w] == b && sidx[w] < bi)) {
                b = sval[w]; bi = sidx[w];
            }
        }
        result = bi;
    }
    __syncthreads();
    const int idx = result;

    // gather: out[row][:] = WT[idx][:]  -- contiguous 4 KB, one float4/lane
    const float4* wt4 = reinterpret_cast<const float4*>(WT + (size_t)idx * OUT_DIM);
    float4* o4 = reinterpret_cast<float4*>(out + (size_t)row * OUT_DIM);
    o4[tid] = wt4[tid];   // 256 lanes x 16 B = 1024 floats
}

// ---------------- R1 fallback (direct column gather) if ws too small ----------------
__global__ __launch_bounds__(BLOCK) void quantizer_fused_direct(
    const float* __restrict__ x,
    const float* __restrict__ W,
    float* __restrict__ out,
    int n_tokens)
{
    const int row = blockIdx.x;
    if (row >= n_tokens) return;
    const int tid = threadIdx.x;
    const float* xr = x + (size_t)row * QUANT_DIM;

    float best = -INFINITY;
    int bidx = 0;
    #pragma unroll
    for (int i = 0; i < QUANT_DIM / (BLOCK * 4); ++i) {
        const int base = i * (BLOCK * 4) + tid * 4;
        const float4 v = *reinterpret_cast<const float4*>(xr + base);
        if (v.x > best) { best = v.x; bidx = base;     }
        if (v.y > best) { best = v.y; bidx = base + 1; }
        if (v.z > best) { best = v.z; bidx = base + 2; }
        if (v.w > best) { best = v.w; bidx = base + 3; }
    }
    #pragma unroll
    for (int off = 32; off > 0; off >>= 1) {
        const float ov = __shfl_down(best, off, 64);
        const int   oi = __shfl_down(bidx, off, 64);
        if (ov > best || (ov == best && oi < bidx)) { best = ov; bidx = oi; }
    }
    __shared__ float sval[BLOCK / 64];
    __shared__ int   sidx[BLOCK / 64];
    __shared__ int   result;
    const int wave = tid >> 6;
    if ((tid & 63) == 0) { sval[wave] = best; sidx[wave] = bidx; }
    __syncthreads();
    if (tid == 0) {
        float b = sval[0];
        int   bi = sidx[0];
        #pragma unroll
        for (int w = 1; w < BLOCK / 64; ++w) {
            if (sval[w] > b || (sval[w] == b && sidx[w] < bi)) {
                b = sval[w]; bi = sidx[w];
            }
        }
        result = bi;
    }
    __syncthreads();
    const int idx = result;
    float* orow = out + (size_t)row * OUT_DIM;
    for (int j = tid; j < OUT_DIM; j += BLOCK) {
        orow[j] = W[(size_t)j * QUANT_DIM + idx];
    }
}

extern "C" void kernel_launch(void* const* d_in, const int* in_sizes, int n_in,
                              void* d_out, int out_size, void* d_ws, size_t ws_size,
                              hipStream_t stream) {
    const float* x = (const float*)d_in[0];
    const float* W = (const float*)d_in[1];
    float* out = (float*)d_out;
    const int n_tokens = in_sizes[0] / QUANT_DIM;
    const size_t wt_bytes = (size_t)QUANT_DIM * OUT_DIM * sizeof(float);

    if (ws_size >= wt_bytes) {
        float* WT = (float*)d_ws;
        dim3 tgrid(QUANT_DIM / TDIM, OUT_DIM / TDIM);
        dim3 tblk(TDIM, 8);
        transpose_W<<<tgrid, tblk, 0, stream>>>(W, WT);
        quantizer_fused_wt<<<n_tokens, BLOCK, 0, stream>>>(x, WT, out, n_tokens);
    } else {
        quantizer_fused_direct<<<n_tokens, BLOCK, 0, stream>>>(x, W, out, n_tokens);
    }
}